// Round 1
// 2998.747 us; speedup vs baseline: 1.2178x; 1.2178x over previous
//
#include <hip/hip_runtime.h>
#include <math.h>

#define S_LEN 2048
#define DK    64
#define TQ    8      // query rows per score block
#define NT    256    // threads per block
#define BH    64     // B*H
#define SCALE 0.125f // 1/sqrt(64)

// ---------------------------------------------------------------------------
// Kernel 1: scores + softmax + W write (fp32 exact path).
// Same proven structure as the previous fused kernel, with the PV phase and
// its 40 KB of LDS (wS + pOut) removed: LDS -> 2.1 KB, occupancy becomes
// VGPR-bound (~16 waves/CU instead of 12), so the 16 per-block softmax
// barriers overlap across more resident blocks.
// ---------------------------------------------------------------------------
__global__ __launch_bounds__(NT) void attn_scores(const float* __restrict__ Q,
                                                  const float* __restrict__ K,
                                                  float* __restrict__ W) {
  __shared__ float4 sQ4[TQ][DK / 4];          // 2 KB
  __shared__ float redm[4], reds[4];

  const int t    = threadIdx.x;
  const int lane = t & 63;
  const int wid  = t >> 6;
  const int bh   = blockIdx.y;
  const int q0   = blockIdx.x * TQ;

  const float* Qb = Q + (size_t)bh * S_LEN * DK;
  const float* Kb = K + (size_t)bh * S_LEN * DK;

  // ---- load Q tile (8x64 fp32) into LDS as float4 ----
  for (int i = t; i < TQ * (DK / 4); i += NT) {
    int r = i / (DK / 4), c = i % (DK / 4);
    sQ4[r][c] = reinterpret_cast<const float4*>(Qb + (size_t)(q0 + r) * DK)[c];
  }
  __syncthreads();

  const int kmax = q0 + TQ;                 // keys beyond this are masked for all rows
  const int jcnt = (kmax + NT - 1) / NT;    // 256-key chunks actually needed (causal skip)

  // ---- scores: thread t owns keys k = t + 256*j ----
  float sc[TQ][8];
#pragma unroll
  for (int r = 0; r < TQ; ++r)
#pragma unroll
    for (int j = 0; j < 8; ++j) sc[r][j] = 0.f;

#pragma unroll
  for (int j = 0; j < 8; ++j) {
    if (j < jcnt) {                         // block-uniform branch
      const int k = t + NT * j;
      const float4* kp = reinterpret_cast<const float4*>(Kb + (size_t)k * DK);
#pragma unroll
      for (int dc = 0; dc < 4; ++dc) {
        float4 k0 = kp[dc * 4 + 0], k1 = kp[dc * 4 + 1];
        float4 k2 = kp[dc * 4 + 2], k3 = kp[dc * 4 + 3];
#pragma unroll
        for (int r = 0; r < TQ; ++r) {
          float4 qa = sQ4[r][dc * 4 + 0], qb = sQ4[r][dc * 4 + 1];
          float4 qc = sQ4[r][dc * 4 + 2], qd = sQ4[r][dc * 4 + 3];
          sc[r][j] += k0.x * qa.x + k0.y * qa.y + k0.z * qa.z + k0.w * qa.w
                    + k1.x * qb.x + k1.y * qb.y + k1.z * qb.z + k1.w * qb.w
                    + k2.x * qc.x + k2.y * qc.y + k2.z * qc.z + k2.w * qc.w
                    + k3.x * qd.x + k3.y * qd.y + k3.z * qd.z + k3.w * qd.w;
        }
      }
    }
  }

  // ---- per-row softmax + weights write (full 2048 cols incl. causal zeros) ----
  float* Wbase = W + (size_t)bh * S_LEN * S_LEN;
#pragma unroll 1
  for (int r = 0; r < TQ; ++r) {
    const int row = q0 + r;
    float m = -INFINITY;
#pragma unroll
    for (int j = 0; j < 8; ++j) {
      int k = t + NT * j;
      float s = (k <= row) ? sc[r][j] * SCALE : -INFINITY;  // j>=jcnt auto-masked (k>row)
      sc[r][j] = s;
      m = fmaxf(m, s);
    }
#pragma unroll
    for (int off = 32; off > 0; off >>= 1) m = fmaxf(m, __shfl_down(m, off, 64));
    if (lane == 0) redm[wid] = m;
    __syncthreads();
    const float M = fmaxf(fmaxf(redm[0], redm[1]), fmaxf(redm[2], redm[3]));

    float ssum = 0.f;
#pragma unroll
    for (int j = 0; j < 8; ++j) {
      float e = __expf(sc[r][j] - M);   // exp(-inf)=0
      sc[r][j] = e;
      ssum += e;
    }
#pragma unroll
    for (int off = 32; off > 0; off >>= 1) ssum += __shfl_down(ssum, off, 64);
    if (lane == 0) reds[wid] = ssum;
    __syncthreads();
    const float inv = 1.f / (reds[0] + reds[1] + reds[2] + reds[3]);

    float* Wrow = Wbase + (size_t)row * S_LEN;
#pragma unroll
    for (int j = 0; j < 8; ++j) {
      int k = t + NT * j;
      Wrow[k] = sc[r][j] * inv;         // covers all 2048 cols incl. zeros
    }
  }
}

// ---------------------------------------------------------------------------
// Kernel 2: Out = W x V as a dense fp32 GEMM per (bh, 64-row tile).
// Reads W back from global (it is an output anyway). 64x64 out tile,
// 64-wide k-tiles in LDS; each thread owns a 4x4 frag -> 64 FMA per
// 8 ds_read_b128. Causality: k-tiles run only up to the diagonal tile;
// zeros inside the diagonal tile are multiplied (harmless).
// Big-k tiles are launched first (reversed blockIdx.x) to shrink the tail.
// ---------------------------------------------------------------------------
#define TM 64
#define TK 64

__global__ __launch_bounds__(NT) void attn_pv(const float* __restrict__ V,
                                              const float* __restrict__ W,
                                              float* __restrict__ Out) {
  __shared__ float sW[TM][TK + 4];   // [q][k], pad 16B
  __shared__ float sV[TK][DK + 4];   // [k][d], pad 16B

  const int t  = threadIdx.x;
  const int bh = blockIdx.y;
  const int qt = (int)gridDim.x - 1 - (int)blockIdx.x;  // big tiles first
  const int q0 = qt * TM;
  const int tx = t & 15;             // d-group (4 cols)
  const int ty = t >> 4;             // q-group (4 rows)
  const int r0 = t >> 4, c4 = t & 15;

  const float* Wb = W + (size_t)bh * S_LEN * S_LEN;
  const float* Vb = V + (size_t)bh * S_LEN * DK;

  float acc[4][4];
#pragma unroll
  for (int i = 0; i < 4; ++i)
#pragma unroll
    for (int j = 0; j < 4; ++j) acc[i][j] = 0.f;

  const int nkt = qt + 1;            // k-tiles covering k <= q0+63
  for (int kt = 0; kt < nkt; ++kt) {
    const int k0 = kt * TK;
    __syncthreads();                 // protect LDS reuse from previous iter
#pragma unroll
    for (int i = 0; i < 4; ++i) {
      int r = r0 + i * 16;
      float4 w4 = *reinterpret_cast<const float4*>(&Wb[(size_t)(q0 + r) * S_LEN + k0 + c4 * 4]);
      *reinterpret_cast<float4*>(&sW[r][c4 * 4]) = w4;
      float4 v4 = *reinterpret_cast<const float4*>(&Vb[(size_t)(k0 + r) * DK + c4 * 4]);
      *reinterpret_cast<float4*>(&sV[r][c4 * 4]) = v4;
    }
    __syncthreads();

#pragma unroll 4
    for (int kk = 0; kk < TK; kk += 4) {
      float4 a0 = *reinterpret_cast<const float4*>(&sW[ty * 4 + 0][kk]);  // broadcast reads
      float4 a1 = *reinterpret_cast<const float4*>(&sW[ty * 4 + 1][kk]);
      float4 a2 = *reinterpret_cast<const float4*>(&sW[ty * 4 + 2][kk]);
      float4 a3 = *reinterpret_cast<const float4*>(&sW[ty * 4 + 3][kk]);
      float4 b0 = *reinterpret_cast<const float4*>(&sV[kk + 0][tx * 4]);
      float4 b1 = *reinterpret_cast<const float4*>(&sV[kk + 1][tx * 4]);
      float4 b2 = *reinterpret_cast<const float4*>(&sV[kk + 2][tx * 4]);
      float4 b3 = *reinterpret_cast<const float4*>(&sV[kk + 3][tx * 4]);

      acc[0][0] += a0.x * b0.x + a0.y * b1.x + a0.z * b2.x + a0.w * b3.x;
      acc[0][1] += a0.x * b0.y + a0.y * b1.y + a0.z * b2.y + a0.w * b3.y;
      acc[0][2] += a0.x * b0.z + a0.y * b1.z + a0.z * b2.z + a0.w * b3.z;
      acc[0][3] += a0.x * b0.w + a0.y * b1.w + a0.z * b2.w + a0.w * b3.w;

      acc[1][0] += a1.x * b0.x + a1.y * b1.x + a1.z * b2.x + a1.w * b3.x;
      acc[1][1] += a1.x * b0.y + a1.y * b1.y + a1.z * b2.y + a1.w * b3.y;
      acc[1][2] += a1.x * b0.z + a1.y * b1.z + a1.z * b2.z + a1.w * b3.z;
      acc[1][3] += a1.x * b0.w + a1.y * b1.w + a1.z * b2.w + a1.w * b3.w;

      acc[2][0] += a2.x * b0.x + a2.y * b1.x + a2.z * b2.x + a2.w * b3.x;
      acc[2][1] += a2.x * b0.y + a2.y * b1.y + a2.z * b2.y + a2.w * b3.y;
      acc[2][2] += a2.x * b0.z + a2.y * b1.z + a2.z * b2.z + a2.w * b3.z;
      acc[2][3] += a2.x * b0.w + a2.y * b1.w + a2.z * b2.w + a2.w * b3.w;

      acc[3][0] += a3.x * b0.x + a3.y * b1.x + a3.z * b2.x + a3.w * b3.x;
      acc[3][1] += a3.x * b0.y + a3.y * b1.y + a3.z * b2.y + a3.w * b3.y;
      acc[3][2] += a3.x * b0.z + a3.y * b1.z + a3.z * b2.z + a3.w * b3.z;
      acc[3][3] += a3.x * b0.w + a3.y * b1.w + a3.z * b2.w + a3.w * b3.w;
    }
  }

  float* Ob = Out + ((size_t)bh * S_LEN + q0) * DK;
#pragma unroll
  for (int i = 0; i < 4; ++i) {
    float4 o;
    o.x = acc[i][0]; o.y = acc[i][1]; o.z = acc[i][2]; o.w = acc[i][3];
    *reinterpret_cast<float4*>(&Ob[(size_t)(ty * 4 + i) * DK + tx * 4]) = o;
  }
}

extern "C" void kernel_launch(void* const* d_in, const int* in_sizes, int n_in,
                              void* d_out, int out_size, void* d_ws, size_t ws_size,
                              hipStream_t stream) {
  const float* Q = (const float*)d_in[0];
  const float* K = (const float*)d_in[1];
  const float* V = (const float*)d_in[2];
  // d_in[3] is the causal tril mask; handled analytically as k <= q.
  float* Out = (float*)d_out;
  float* W   = Out + (size_t)BH * S_LEN * DK;  // out first, then weights

  dim3 g1(S_LEN / TQ, BH);
  attn_scores<<<g1, NT, 0, stream>>>(Q, K, W);

  dim3 g2(S_LEN / TM, BH);
  attn_pv<<<g2, NT, 0, stream>>>(V, W, Out);
}

// Round 2
// 2046.101 us; speedup vs baseline: 1.7848x; 1.4656x over previous
//
#include <hip/hip_runtime.h>
#include <math.h>

#define S_LEN 2048
#define DK    64
#define TQ    8      // query rows per score block
#define NT    256    // threads per block
#define BH    64     // B*H
#define SCALE 0.125f // 1/sqrt(64)

typedef __attribute__((ext_vector_type(8))) short short8;  // 8 bf16 (4 VGPRs)
typedef __attribute__((ext_vector_type(4))) float f32x4;   // MFMA C/D frag

// RNE fp32 -> bf16 pair packed into one u32 (lo in bits 0-15, hi in 16-31).
__device__ __forceinline__ unsigned int pack_bf16_2(float lo, float hi) {
  unsigned int ulo = __float_as_uint(lo);
  unsigned int uhi = __float_as_uint(hi);
  ulo = (ulo + 0x7fffu + ((ulo >> 16) & 1u)) >> 16;
  uhi = (uhi + 0x7fffu + ((uhi >> 16) & 1u)) & 0xffff0000u;
  return ulo | uhi;
}

// ---------------------------------------------------------------------------
// Kernel 1: scores + softmax + W write (fp32 exact path).
// Fix vs prev round: softmax r-loop fully unrolled -> sc[][] statically
// indexed -> stays in VGPRs (prev: runtime r -> scratch -> 5.5 GB of HBM
// write amplification, VGPR_Count=32 was the tell). Reductions batched:
// 2 barriers per block instead of 16.
// ---------------------------------------------------------------------------
__global__ __launch_bounds__(NT, 3) void attn_scores(const float* __restrict__ Q,
                                                     const float* __restrict__ K,
                                                     float* __restrict__ W) {
  __shared__ float4 sQ4[TQ][DK / 4];          // 2 KB
  __shared__ float redm[TQ][4], reds[TQ][4];  // 256 B

  const int t    = threadIdx.x;
  const int lane = t & 63;
  const int wid  = t >> 6;
  const int bh   = blockIdx.y;
  const int q0   = blockIdx.x * TQ;

  const float* Qb = Q + (size_t)bh * S_LEN * DK;
  const float* Kb = K + (size_t)bh * S_LEN * DK;

  // ---- load Q tile (8x64 fp32) into LDS as float4 ----
  for (int i = t; i < TQ * (DK / 4); i += NT) {
    int r = i / (DK / 4), c = i % (DK / 4);
    sQ4[r][c] = reinterpret_cast<const float4*>(Qb + (size_t)(q0 + r) * DK)[c];
  }
  __syncthreads();

  const int kmax = q0 + TQ;
  const int jcnt = (kmax + NT - 1) / NT;    // causal skip: 256-key chunks needed

  // ---- scores: thread t owns keys k = t + 256*j ----
  float sc[TQ][8];
#pragma unroll
  for (int r = 0; r < TQ; ++r)
#pragma unroll
    for (int j = 0; j < 8; ++j) sc[r][j] = 0.f;

#pragma unroll
  for (int j = 0; j < 8; ++j) {
    if (j < jcnt) {                         // block-uniform branch
      const int k = t + NT * j;
      const float4* kp = reinterpret_cast<const float4*>(Kb + (size_t)k * DK);
#pragma unroll
      for (int dc = 0; dc < 4; ++dc) {
        float4 k0 = kp[dc * 4 + 0], k1 = kp[dc * 4 + 1];
        float4 k2 = kp[dc * 4 + 2], k3 = kp[dc * 4 + 3];
#pragma unroll
        for (int r = 0; r < TQ; ++r) {
          float4 qa = sQ4[r][dc * 4 + 0], qb = sQ4[r][dc * 4 + 1];
          float4 qc = sQ4[r][dc * 4 + 2], qd = sQ4[r][dc * 4 + 3];
          sc[r][j] += k0.x * qa.x + k0.y * qa.y + k0.z * qa.z + k0.w * qa.w
                    + k1.x * qb.x + k1.y * qb.y + k1.z * qb.z + k1.w * qb.w
                    + k2.x * qc.x + k2.y * qc.y + k2.z * qc.z + k2.w * qc.w
                    + k3.x * qd.x + k3.y * qd.y + k3.z * qd.z + k3.w * qd.w;
        }
      }
    }
  }

  // ---- pass A: mask+scale, per-row wave max, store partials ----
#pragma unroll
  for (int r = 0; r < TQ; ++r) {
    const int row = q0 + r;
    float m = -INFINITY;
#pragma unroll
    for (int j = 0; j < 8; ++j) {
      int k = t + NT * j;
      float s = (k <= row) ? sc[r][j] * SCALE : -INFINITY;
      sc[r][j] = s;
      m = fmaxf(m, s);
    }
#pragma unroll
    for (int off = 32; off > 0; off >>= 1) m = fmaxf(m, __shfl_down(m, off, 64));
    if (lane == 0) redm[r][wid] = m;
  }
  __syncthreads();

  // ---- pass B: exp + per-row wave sum ----
#pragma unroll
  for (int r = 0; r < TQ; ++r) {
    const float M = fmaxf(fmaxf(redm[r][0], redm[r][1]), fmaxf(redm[r][2], redm[r][3]));
    float ssum = 0.f;
#pragma unroll
    for (int j = 0; j < 8; ++j) {
      float e = __expf(sc[r][j] - M);   // exp(-inf)=0
      sc[r][j] = e;
      ssum += e;
    }
#pragma unroll
    for (int off = 32; off > 0; off >>= 1) ssum += __shfl_down(ssum, off, 64);
    if (lane == 0) reds[r][wid] = ssum;
  }
  __syncthreads();

  // ---- pass C: normalize + write full rows (incl. causal zeros) ----
  float* Wbase = W + (size_t)bh * S_LEN * S_LEN;
#pragma unroll
  for (int r = 0; r < TQ; ++r) {
    const float inv = 1.f / (reds[r][0] + reds[r][1] + reds[r][2] + reds[r][3]);
    float* Wrow = Wbase + (size_t)(q0 + r) * S_LEN;
#pragma unroll
    for (int j = 0; j < 8; ++j) Wrow[t + NT * j] = sc[r][j] * inv;
  }
}

// ---------------------------------------------------------------------------
// Kernel 2: Out = W x V via bf16 MFMA (16x16x32). 64x64 out tile per block,
// 4 waves: wave w owns rows [16w,16w+16) x all 64 cols (4 n-frags).
// W staged to LDS as bf16 with XOR swizzle ((row&7)<<4) -> ds_read_b128
// A-frags conflict-light. V staged row-major [k][d] bf16; B-frags built by
// 8x ds_read_u16 (k-major per lane). Fragment layouts (guide §3, m89):
//   A[row=l&15][k=(l>>4)*8+i], B[k=(l>>4)*8+i][col=l&15],
//   D: col=lane&15, row=(lane>>4)*4+reg.
// Causal: only tiles kt <= qt; diagonal tile's upper part is exact zeros in W.
// ---------------------------------------------------------------------------
#define PTM 64
#define PKT 64

__global__ __launch_bounds__(NT) void attn_pv(const float* __restrict__ V,
                                              const float* __restrict__ W,
                                              float* __restrict__ Out) {
  __shared__ __align__(16) unsigned short sW[PTM * PKT];  // 8 KB, swizzled rows (128 B)
  __shared__ __align__(16) unsigned short sV[PKT * DK];   // 8 KB, [k][d] row-major

  const int t  = threadIdx.x;
  const int l  = t & 63;
  const int w  = t >> 6;
  const int bh = blockIdx.y;
  const int qt = (int)gridDim.x - 1 - (int)blockIdx.x;  // big-k tiles first
  const int q0 = qt * PTM;
  const int lr = t >> 4;   // 0..15
  const int lc = t & 15;   // 0..15

  const float* Wb = W + (size_t)bh * S_LEN * S_LEN;
  const float* Vb = V + (size_t)bh * S_LEN * DK;

  f32x4 acc[4];
#pragma unroll
  for (int nf = 0; nf < 4; ++nf) acc[nf] = (f32x4){0.f, 0.f, 0.f, 0.f};

  const int nkt = qt + 1;
  for (int kt = 0; kt < nkt; ++kt) {
    const int k0 = kt * PKT;
    __syncthreads();   // protect LDS from previous iteration's readers
#pragma unroll
    for (int ii = 0; ii < 4; ++ii) {
      const int r = ii * 16 + lr;          // row within tile (q-row for W, k-row for V)
      float4 wv = *reinterpret_cast<const float4*>(&Wb[(size_t)(q0 + r) * S_LEN + k0 + lc * 4]);
      uint2 wp;
      wp.x = pack_bf16_2(wv.x, wv.y);
      wp.y = pack_bf16_2(wv.z, wv.w);
      const int wbyte = (lc * 8) ^ ((r & 7) << 4);   // XOR swizzle within 128 B row
      *reinterpret_cast<uint2*>(reinterpret_cast<char*>(sW) + r * 128 + wbyte) = wp;

      float4 vv = *reinterpret_cast<const float4*>(&Vb[(size_t)(k0 + r) * DK + lc * 4]);
      uint2 vp;
      vp.x = pack_bf16_2(vv.x, vv.y);
      vp.y = pack_bf16_2(vv.z, vv.w);
      *reinterpret_cast<uint2*>(reinterpret_cast<char*>(sV) + r * 128 + lc * 8) = vp;
    }
    __syncthreads();

    const int arow = w * 16 + (l & 15);
    const char* aRow = reinterpret_cast<const char*>(sW) + arow * 128;
    const int aswz = (arow & 7) << 4;
#pragma unroll
    for (int ks = 0; ks < 2; ++ks) {
      short8 a = *reinterpret_cast<const short8*>(aRow + ((ks * 64 + (l >> 4) * 16) ^ aswz));
      const int kbase = ks * 32 + (l >> 4) * 8;
#pragma unroll
      for (int nf = 0; nf < 4; ++nf) {
        union { short8 v; unsigned short u[8]; } b;
#pragma unroll
        for (int i = 0; i < 8; ++i)
          b.u[i] = sV[(kbase + i) * DK + nf * 16 + (l & 15)];
        acc[nf] = __builtin_amdgcn_mfma_f32_16x16x32_bf16(a, b.v, acc[nf], 0, 0, 0);
      }
    }
  }

  float* Ob = Out + ((size_t)bh * S_LEN + q0) * DK;
#pragma unroll
  for (int nf = 0; nf < 4; ++nf) {
#pragma unroll
    for (int reg = 0; reg < 4; ++reg) {
      const int row = w * 16 + (l >> 4) * 4 + reg;
      const int col = nf * 16 + (l & 15);
      Ob[(size_t)row * DK + col] = acc[nf][reg];
    }
  }
}

extern "C" void kernel_launch(void* const* d_in, const int* in_sizes, int n_in,
                              void* d_out, int out_size, void* d_ws, size_t ws_size,
                              hipStream_t stream) {
  const float* Q = (const float*)d_in[0];
  const float* K = (const float*)d_in[1];
  const float* V = (const float*)d_in[2];
  // d_in[3] is the causal tril mask; handled analytically as k <= q.
  float* Out = (float*)d_out;
  float* W   = Out + (size_t)BH * S_LEN * DK;  // out first, then weights

  dim3 g1(S_LEN / TQ, BH);
  attn_scores<<<g1, NT, 0, stream>>>(Q, K, W);

  dim3 g2(S_LEN / PTM, BH);
  attn_pv<<<g2, NT, 0, stream>>>(V, W, Out);
}